// Round 1
// baseline (506.999 us; speedup 1.0000x reference)
//
#include <hip/hip_runtime.h>
#include <hip/hip_bf16.h>
#include <stdint.h>

// GCN 2-layer + linear head, fp32.
// Pipeline:
//  0. detect edge_index dtype (int64 vs int32)           <<<1,1>>>
//  1. zero degree counts
//  2. count in-degrees + convert edge index to int32
//  3. scanA: per-block exclusive scan of counts (+ dinv = rsqrt(count+1))
//  4. scanB: scan of block totals (single block)
//  5. scanC: finalize offsets, init cursor
//  6. fill CSR (csr[pos] = src, grouped by dst)
//  7. gemm1: hs1 = (x @ W1) * dinv[row]          [N,64]
//  8. agg1 : h1post = relu(dinv*(self+gather) + b1)      [N,64]  (wave/node)
//  9. gemm2: hs2 = (h1post @ W2) * dinv[row]     [N,32]
// 10. agg2 : out = relu(dinv*(self+gather)+b2) . Wfc + bfc  (wave/node, fused head)

#define THREADS 256

__global__ void k_detect_dtype(const unsigned int* ei_words, int* flag) {
    // int64 little-endian with values < 2^31  ->  every odd 32-bit word is 0.
    int is64 = 1;
    for (int i = 1; i < 64; i += 2) {
        if (ei_words[i] != 0u) { is64 = 0; break; }
    }
    *flag = is64;
}

__global__ void k_zero_int(int* p, int n) {
    int i = blockIdx.x * blockDim.x + threadIdx.x;
    if (i < n) p[i] = 0;
}

__global__ void k_count_edges(const void* ei, const int* flag,
                              int* count, int* src32, int* dst32, int E) {
    int e = blockIdx.x * blockDim.x + threadIdx.x;
    if (e >= E) return;
    int s, d;
    if (*flag) {
        const long long* p = (const long long*)ei;
        s = (int)p[e];
        d = (int)p[(size_t)E + e];
    } else {
        const int* p = (const int*)ei;
        s = p[e];
        d = p[E + e];
    }
    src32[e] = s;
    dst32[e] = d;
    atomicAdd(&count[d], 1);
}

// Per-block exclusive scan; writes per-block partial scans + block totals + dinv.
__global__ void k_scanA(const int* count, int* offsets, int* totals, float* dinv, int n) {
    __shared__ int s[THREADS];
    int t = threadIdx.x;
    int i = blockIdx.x * THREADS + t;
    int c = (i < n) ? count[i] : 0;
    s[t] = c;
    __syncthreads();
    for (int off = 1; off < THREADS; off <<= 1) {
        int v = (t >= off) ? s[t - off] : 0;
        __syncthreads();
        s[t] += v;
        __syncthreads();
    }
    if (i < n) {
        offsets[i] = s[t] - c;                       // exclusive within block
        dinv[i] = rsqrtf((float)(c + 1));            // deg includes self loop
    }
    if (t == THREADS - 1) totals[blockIdx.x] = s[t];
}

// Single-block scan of up to 512 block totals (NB = ceil(100000/256) = 391 <= 512).
__global__ void k_scanB(int* totals, int nb) {
    __shared__ int s[512];
    int t = threadIdx.x;
    int c = (t < nb) ? totals[t] : 0;
    s[t] = c;
    __syncthreads();
    for (int off = 1; off < 512; off <<= 1) {
        int v = (t >= off) ? s[t - off] : 0;
        __syncthreads();
        s[t] += v;
        __syncthreads();
    }
    if (t < nb) totals[t] = s[t] - c;                // exclusive
}

__global__ void k_scanC(int* offsets, const int* totals, int* cursor, int n) {
    int i = blockIdx.x * blockDim.x + threadIdx.x;
    if (i >= n) return;
    int v = offsets[i] + totals[blockIdx.x];
    offsets[i] = v;
    cursor[i] = v;
}

__global__ void k_fill_csr(const int* src32, const int* dst32, int* cursor, int* csr, int E) {
    int e = blockIdx.x * blockDim.x + threadIdx.x;
    if (e >= E) return;
    int d = dst32[e];
    int pos = atomicAdd(&cursor[d], 1);
    csr[pos] = src32[e];
}

// hs1[r][j] = dinv[r] * sum_k x[r][k] * W1[k][j]   (x: [n,128], W1: [128,64])
__global__ void __launch_bounds__(THREADS, 2) k_gemm1(const float* __restrict__ x,
                                                      const float* __restrict__ W1,
                                                      const float* __restrict__ dinv,
                                                      float* __restrict__ hs1, int n) {
    __shared__ float Ws[128 * 64];
    int t = threadIdx.x;
    #pragma unroll
    for (int i = 0; i < 8; ++i) {
        int idx = t + i * THREADS;                   // 2048 float4 total
        ((float4*)Ws)[idx] = ((const float4*)W1)[idx];
    }
    __syncthreads();

    int r = blockIdx.x * THREADS + t;
    if (r >= n) return;

    float4 acc[16];
    #pragma unroll
    for (int j = 0; j < 16; ++j) acc[j] = make_float4(0.f, 0.f, 0.f, 0.f);

    const float* xrow = x + (size_t)r * 128;
    for (int kk = 0; kk < 128; kk += 32) {
        float4 xv[8];
        #pragma unroll
        for (int q = 0; q < 8; ++q) xv[q] = ((const float4*)(xrow + kk))[q];
        #pragma unroll
        for (int c = 0; c < 32; ++c) {
            const float4 v = xv[c >> 2];
            const int m = c & 3;
            const float xc = (m == 0) ? v.x : (m == 1) ? v.y : (m == 2) ? v.z : v.w;
            const float4* wrow = (const float4*)(Ws + (kk + c) * 64);
            #pragma unroll
            for (int j = 0; j < 16; ++j) {
                float4 w = wrow[j];
                acc[j].x = fmaf(xc, w.x, acc[j].x);
                acc[j].y = fmaf(xc, w.y, acc[j].y);
                acc[j].z = fmaf(xc, w.z, acc[j].z);
                acc[j].w = fmaf(xc, w.w, acc[j].w);
            }
        }
    }
    float dv = dinv[r];
    float4* orow = (float4*)(hs1 + (size_t)r * 64);
    #pragma unroll
    for (int j = 0; j < 16; ++j) {
        float4 a = acc[j];
        orow[j] = make_float4(a.x * dv, a.y * dv, a.z * dv, a.w * dv);
    }
}

// One wave per node, lane = feature (64). acc = hs1[node] + sum_in hs1[src];
// h1post = relu(dinv[node]*acc + b1).
__global__ void k_agg1(const float* __restrict__ hs1, const int* __restrict__ csr,
                       const int* __restrict__ offsets, const int* __restrict__ count,
                       const float* __restrict__ dinv, const float* __restrict__ b1,
                       float* __restrict__ h1post, int n) {
    int wid = threadIdx.x >> 6;
    int lane = threadIdx.x & 63;
    int node = blockIdx.x * 4 + wid;
    if (node >= n) return;
    int s = offsets[node];
    int c = count[node];
    float acc = hs1[(size_t)node * 64 + lane];
    for (int j = 0; j < c; ++j) {
        int src = csr[s + j];
        acc += hs1[(size_t)src * 64 + lane];
    }
    float v = dinv[node] * acc + b1[lane];
    h1post[(size_t)node * 64 + lane] = fmaxf(v, 0.f);
}

// hs2[r][j] = dinv[r] * sum_k h1post[r][k] * W2[k][j]   (W2: [64,32])
__global__ void __launch_bounds__(THREADS, 2) k_gemm2(const float* __restrict__ h1,
                                                      const float* __restrict__ W2,
                                                      const float* __restrict__ dinv,
                                                      float* __restrict__ hs2, int n) {
    __shared__ float Ws[64 * 32];
    int t = threadIdx.x;
    #pragma unroll
    for (int i = 0; i < 2; ++i) {
        int idx = t + i * THREADS;                   // 512 float4 total
        ((float4*)Ws)[idx] = ((const float4*)W2)[idx];
    }
    __syncthreads();

    int r = blockIdx.x * THREADS + t;
    if (r >= n) return;

    float4 acc[8];
    #pragma unroll
    for (int j = 0; j < 8; ++j) acc[j] = make_float4(0.f, 0.f, 0.f, 0.f);

    const float* xrow = h1 + (size_t)r * 64;
    for (int kk = 0; kk < 64; kk += 32) {
        float4 xv[8];
        #pragma unroll
        for (int q = 0; q < 8; ++q) xv[q] = ((const float4*)(xrow + kk))[q];
        #pragma unroll
        for (int c = 0; c < 32; ++c) {
            const float4 v = xv[c >> 2];
            const int m = c & 3;
            const float xc = (m == 0) ? v.x : (m == 1) ? v.y : (m == 2) ? v.z : v.w;
            const float4* wrow = (const float4*)(Ws + (kk + c) * 32);
            #pragma unroll
            for (int j = 0; j < 8; ++j) {
                float4 w = wrow[j];
                acc[j].x = fmaf(xc, w.x, acc[j].x);
                acc[j].y = fmaf(xc, w.y, acc[j].y);
                acc[j].z = fmaf(xc, w.z, acc[j].z);
                acc[j].w = fmaf(xc, w.w, acc[j].w);
            }
        }
    }
    float dv = dinv[r];
    float4* orow = (float4*)(hs2 + (size_t)r * 32);
    #pragma unroll
    for (int j = 0; j < 8; ++j) {
        float4 a = acc[j];
        orow[j] = make_float4(a.x * dv, a.y * dv, a.z * dv, a.w * dv);
    }
}

// One wave per node; lanes 0-31 = features with even edges, lanes 32-63 = same
// features with odd edges. Fold, add self, relu(dinv*acc+b2), dot Wfc, + bfc.
__global__ void k_agg2_head(const float* __restrict__ hs2, const int* __restrict__ csr,
                            const int* __restrict__ offsets, const int* __restrict__ count,
                            const float* __restrict__ dinv, const float* __restrict__ b2,
                            const float* __restrict__ Wfc, const float* __restrict__ bfc,
                            float* __restrict__ out, int n) {
    int wid = threadIdx.x >> 6;
    int lane = threadIdx.x & 63;
    int node = blockIdx.x * 4 + wid;
    if (node >= n) return;
    int f = lane & 31;
    int half = lane >> 5;
    int s = offsets[node];
    int c = count[node];
    float acc = 0.f;
    for (int j = half; j < c; j += 2) {
        int src = csr[s + j];
        acc += hs2[(size_t)src * 32 + f];
    }
    acc += __shfl_xor(acc, 32);                      // fold odd/even edge halves
    acc += hs2[(size_t)node * 32 + f];               // self loop
    float h = fmaxf(dinv[node] * acc + b2[f], 0.f);
    float p = h * Wfc[f];
    #pragma unroll
    for (int m = 16; m >= 1; m >>= 1) p += __shfl_xor(p, m);
    if (lane == 0) out[node] = p + bfc[0];
}

extern "C" void kernel_launch(void* const* d_in, const int* in_sizes, int n_in,
                              void* d_out, int out_size, void* d_ws, size_t ws_size,
                              hipStream_t stream) {
    const float* x   = (const float*)d_in[0];
    const void*  ei  = d_in[1];                      // int64 or int32, detected on device
    const float* W1  = (const float*)d_in[2];
    const float* b1  = (const float*)d_in[3];
    const float* W2  = (const float*)d_in[4];
    const float* b2  = (const float*)d_in[5];
    const float* Wfc = (const float*)d_in[6];
    const float* bfc = (const float*)d_in[7];
    float* out = (float*)d_out;

    const int n = in_sizes[0] / 128;                 // 100000
    const int E = in_sizes[1] / 2;                   // 1600000

    // ---- workspace carve ----
    size_t off = 0;
    auto alloc = [&](size_t bytes) -> void* {
        void* p = (char*)d_ws + off;
        off += (bytes + 255) & ~(size_t)255;
        return p;
    };
    int*   count   = (int*)  alloc((size_t)n * 4);
    int*   offsets = (int*)  alloc((size_t)n * 4);
    int*   cursor  = (int*)  alloc((size_t)n * 4);
    int*   totals  = (int*)  alloc(512 * 4);
    float* dinv    = (float*)alloc((size_t)n * 4);
    int*   src32   = (int*)  alloc((size_t)E * 4);
    int*   dst32   = (int*)  alloc((size_t)E * 4);
    int*   csr     = (int*)  alloc((size_t)E * 4);
    float* hs1     = (float*)alloc((size_t)n * 64 * 4);
    float* h1post  = (float*)alloc((size_t)n * 64 * 4);
    float* hs2     = (float*)alloc((size_t)n * 32 * 4);
    int*   flag    = (int*)  alloc(4);
    (void)ws_size;

    const int NB = (n + THREADS - 1) / THREADS;      // 391 (<= 512 required by scanB)
    const int EB = (E + THREADS - 1) / THREADS;
    const int AG = (n + 3) / 4;                      // 4 waves (nodes) per block

    k_detect_dtype<<<1, 1, 0, stream>>>((const unsigned int*)ei, flag);
    k_zero_int<<<NB, THREADS, 0, stream>>>(count, n);
    k_count_edges<<<EB, THREADS, 0, stream>>>(ei, flag, count, src32, dst32, E);
    k_scanA<<<NB, THREADS, 0, stream>>>(count, offsets, totals, dinv, n);
    k_scanB<<<1, 512, 0, stream>>>(totals, NB);
    k_scanC<<<NB, THREADS, 0, stream>>>(offsets, totals, cursor, n);
    k_fill_csr<<<EB, THREADS, 0, stream>>>(src32, dst32, cursor, csr, E);
    k_gemm1<<<NB, THREADS, 0, stream>>>(x, W1, dinv, hs1, n);
    k_agg1<<<AG, THREADS, 0, stream>>>(hs1, csr, offsets, count, dinv, b1, h1post, n);
    k_gemm2<<<NB, THREADS, 0, stream>>>(h1post, W2, dinv, hs2, n);
    k_agg2_head<<<AG, THREADS, 0, stream>>>(hs2, csr, offsets, count, dinv, b2, Wfc, bfc, out, n);
}

// Round 2
// 362.189 us; speedup vs baseline: 1.3998x; 1.3998x over previous
//
#include <hip/hip_runtime.h>
#include <hip/hip_bf16.h>
#include <stdint.h>

// GCN 2-layer + linear head, fp32.
// Pipeline:
//  0. detect edge_index dtype (int64 vs int32)           <<<1,1>>>
//  1. zero degree counts
//  2. count in-degrees + convert edge index to int32
//  3. scanA: per-block exclusive scan of counts (+ dinv = rsqrt(count+1))
//  4. scanB: scan of block totals (single block)
//  5. scanC: finalize offsets, init cursor
//  6. fill CSR (csr[pos] = src, grouped by dst)
//  7. gemm1: hs1 = (x @ W1) * dinv[row]          [N,64]
//  8. agg1 : h1post = relu(dinv*(self+gather) + b1)      [N,64]  (wave/node, 4-edge-wide)
//  9. gemm2: hs2 = (h1post @ W2) * dinv[row]     [N,32]
// 10. agg2 : out = relu(dinv*(self+gather)+b2) . Wfc + bfc  (wave/node, 8-edge-wide)

#define THREADS 256

__global__ void k_detect_dtype(const unsigned int* ei_words, int* flag) {
    int is64 = 1;
    for (int i = 1; i < 64; i += 2) {
        if (ei_words[i] != 0u) { is64 = 0; break; }
    }
    *flag = is64;
}

__global__ void k_zero_int(int* p, int n) {
    int i = blockIdx.x * blockDim.x + threadIdx.x;
    if (i < n) p[i] = 0;
}

__global__ void k_count_edges(const void* ei, const int* flag,
                              int* count, int* src32, int* dst32, int E) {
    int e = blockIdx.x * blockDim.x + threadIdx.x;
    if (e >= E) return;
    int s, d;
    if (*flag) {
        const long long* p = (const long long*)ei;
        s = (int)p[e];
        d = (int)p[(size_t)E + e];
    } else {
        const int* p = (const int*)ei;
        s = p[e];
        d = p[E + e];
    }
    src32[e] = s;
    dst32[e] = d;
    atomicAdd(&count[d], 1);
}

__global__ void k_scanA(const int* count, int* offsets, int* totals, float* dinv, int n) {
    __shared__ int s[THREADS];
    int t = threadIdx.x;
    int i = blockIdx.x * THREADS + t;
    int c = (i < n) ? count[i] : 0;
    s[t] = c;
    __syncthreads();
    for (int off = 1; off < THREADS; off <<= 1) {
        int v = (t >= off) ? s[t - off] : 0;
        __syncthreads();
        s[t] += v;
        __syncthreads();
    }
    if (i < n) {
        offsets[i] = s[t] - c;
        dinv[i] = rsqrtf((float)(c + 1));
    }
    if (t == THREADS - 1) totals[blockIdx.x] = s[t];
}

__global__ void k_scanB(int* totals, int nb) {
    __shared__ int s[512];
    int t = threadIdx.x;
    int c = (t < nb) ? totals[t] : 0;
    s[t] = c;
    __syncthreads();
    for (int off = 1; off < 512; off <<= 1) {
        int v = (t >= off) ? s[t - off] : 0;
        __syncthreads();
        s[t] += v;
        __syncthreads();
    }
    if (t < nb) totals[t] = s[t] - c;
}

__global__ void k_scanC(int* offsets, const int* totals, int* cursor, int n) {
    int i = blockIdx.x * blockDim.x + threadIdx.x;
    if (i >= n) return;
    int v = offsets[i] + totals[blockIdx.x];
    offsets[i] = v;
    cursor[i] = v;
}

__global__ void k_fill_csr(const int* src32, const int* dst32, int* cursor, int* csr, int E) {
    int e = blockIdx.x * blockDim.x + threadIdx.x;
    if (e >= E) return;
    int d = dst32[e];
    int pos = atomicAdd(&cursor[d], 1);
    csr[pos] = src32[e];
}

// hs1[r][j] = dinv[r] * sum_k x[r][k] * W1[k][j]   (x: [n,128], W1: [128,64])
__global__ void __launch_bounds__(THREADS, 2) k_gemm1(const float* __restrict__ x,
                                                      const float* __restrict__ W1,
                                                      const float* __restrict__ dinv,
                                                      float* __restrict__ hs1, int n) {
    __shared__ float Ws[128 * 64];
    int t = threadIdx.x;
    #pragma unroll
    for (int i = 0; i < 8; ++i) {
        int idx = t + i * THREADS;
        ((float4*)Ws)[idx] = ((const float4*)W1)[idx];
    }
    __syncthreads();

    int r = blockIdx.x * THREADS + t;
    if (r >= n) return;

    float4 acc[16];
    #pragma unroll
    for (int j = 0; j < 16; ++j) acc[j] = make_float4(0.f, 0.f, 0.f, 0.f);

    const float* xrow = x + (size_t)r * 128;
    for (int kk = 0; kk < 128; kk += 32) {
        float4 xv[8];
        #pragma unroll
        for (int q = 0; q < 8; ++q) xv[q] = ((const float4*)(xrow + kk))[q];
        #pragma unroll
        for (int c = 0; c < 32; ++c) {
            const float4 v = xv[c >> 2];
            const int m = c & 3;
            const float xc = (m == 0) ? v.x : (m == 1) ? v.y : (m == 2) ? v.z : v.w;
            const float4* wrow = (const float4*)(Ws + (kk + c) * 64);
            #pragma unroll
            for (int j = 0; j < 16; ++j) {
                float4 w = wrow[j];
                acc[j].x = fmaf(xc, w.x, acc[j].x);
                acc[j].y = fmaf(xc, w.y, acc[j].y);
                acc[j].z = fmaf(xc, w.z, acc[j].z);
                acc[j].w = fmaf(xc, w.w, acc[j].w);
            }
        }
    }
    float dv = dinv[r];
    float4* orow = (float4*)(hs1 + (size_t)r * 64);
    #pragma unroll
    for (int j = 0; j < 16; ++j) {
        float4 a = acc[j];
        orow[j] = make_float4(a.x * dv, a.y * dv, a.z * dv, a.w * dv);
    }
}

// One wave per node. 4 edge-groups x 16 lanes x float4: 4 edges gathered per
// iteration step, unrolled x2 -> 8 outstanding 256B gathers per wave.
__global__ void k_agg1(const float* __restrict__ hs1, const int* __restrict__ csr,
                       const int* __restrict__ offsets, const int* __restrict__ count,
                       const float* __restrict__ dinv, const float* __restrict__ b1,
                       float* __restrict__ h1post, int n) {
    int wid = threadIdx.x >> 6;
    int lane = threadIdx.x & 63;
    int node = blockIdx.x * 4 + wid;
    if (node >= n) return;
    int g  = lane >> 4;                 // edge group 0..3
    int f4 = lane & 15;                 // float4 index within 64-float row
    int s = offsets[node];
    int c = count[node];

    float4 a0 = make_float4(0.f, 0.f, 0.f, 0.f);
    float4 a1 = make_float4(0.f, 0.f, 0.f, 0.f);
    if (g == 0) a0 = ((const float4*)(hs1 + (size_t)node * 64))[f4];  // self loop

    for (int j = 0; j < c; j += 8) {
        int e0 = j + g;
        int e1 = j + 4 + g;
        int i0 = s + min(e0, c - 1);
        int i1 = s + min(e1, c - 1);
        int s0 = csr[i0];
        int s1 = csr[i1];
        float m0 = (e0 < c) ? 1.f : 0.f;
        float m1 = (e1 < c) ? 1.f : 0.f;
        float4 v0 = ((const float4*)(hs1 + (size_t)s0 * 64))[f4];
        float4 v1 = ((const float4*)(hs1 + (size_t)s1 * 64))[f4];
        a0.x = fmaf(m0, v0.x, a0.x); a0.y = fmaf(m0, v0.y, a0.y);
        a0.z = fmaf(m0, v0.z, a0.z); a0.w = fmaf(m0, v0.w, a0.w);
        a1.x = fmaf(m1, v1.x, a1.x); a1.y = fmaf(m1, v1.y, a1.y);
        a1.z = fmaf(m1, v1.z, a1.z); a1.w = fmaf(m1, v1.w, a1.w);
    }
    a0.x += a1.x; a0.y += a1.y; a0.z += a1.z; a0.w += a1.w;
    // fold the 4 edge groups (xor 16, then 32), component-wise
    a0.x += __shfl_xor(a0.x, 16); a0.y += __shfl_xor(a0.y, 16);
    a0.z += __shfl_xor(a0.z, 16); a0.w += __shfl_xor(a0.w, 16);
    a0.x += __shfl_xor(a0.x, 32); a0.y += __shfl_xor(a0.y, 32);
    a0.z += __shfl_xor(a0.z, 32); a0.w += __shfl_xor(a0.w, 32);

    if (g == 0) {
        float dv = dinv[node];
        float4 b = ((const float4*)b1)[f4];
        float4 o;
        o.x = fmaxf(fmaf(dv, a0.x, b.x), 0.f);
        o.y = fmaxf(fmaf(dv, a0.y, b.y), 0.f);
        o.z = fmaxf(fmaf(dv, a0.z, b.z), 0.f);
        o.w = fmaxf(fmaf(dv, a0.w, b.w), 0.f);
        ((float4*)(h1post + (size_t)node * 64))[f4] = o;
    }
}

// hs2[r][j] = dinv[r] * sum_k h1post[r][k] * W2[k][j]   (W2: [64,32])
__global__ void __launch_bounds__(THREADS, 2) k_gemm2(const float* __restrict__ h1,
                                                      const float* __restrict__ W2,
                                                      const float* __restrict__ dinv,
                                                      float* __restrict__ hs2, int n) {
    __shared__ float Ws[64 * 32];
    int t = threadIdx.x;
    #pragma unroll
    for (int i = 0; i < 2; ++i) {
        int idx = t + i * THREADS;
        ((float4*)Ws)[idx] = ((const float4*)W2)[idx];
    }
    __syncthreads();

    int r = blockIdx.x * THREADS + t;
    if (r >= n) return;

    float4 acc[8];
    #pragma unroll
    for (int j = 0; j < 8; ++j) acc[j] = make_float4(0.f, 0.f, 0.f, 0.f);

    const float* xrow = h1 + (size_t)r * 64;
    for (int kk = 0; kk < 64; kk += 32) {
        float4 xv[8];
        #pragma unroll
        for (int q = 0; q < 8; ++q) xv[q] = ((const float4*)(xrow + kk))[q];
        #pragma unroll
        for (int c = 0; c < 32; ++c) {
            const float4 v = xv[c >> 2];
            const int m = c & 3;
            const float xc = (m == 0) ? v.x : (m == 1) ? v.y : (m == 2) ? v.z : v.w;
            const float4* wrow = (const float4*)(Ws + (kk + c) * 32);
            #pragma unroll
            for (int j = 0; j < 8; ++j) {
                float4 w = wrow[j];
                acc[j].x = fmaf(xc, w.x, acc[j].x);
                acc[j].y = fmaf(xc, w.y, acc[j].y);
                acc[j].z = fmaf(xc, w.z, acc[j].z);
                acc[j].w = fmaf(xc, w.w, acc[j].w);
            }
        }
    }
    float dv = dinv[r];
    float4* orow = (float4*)(hs2 + (size_t)r * 32);
    #pragma unroll
    for (int j = 0; j < 8; ++j) {
        float4 a = acc[j];
        orow[j] = make_float4(a.x * dv, a.y * dv, a.z * dv, a.w * dv);
    }
}

// One wave per node. 8 edge-groups x 8 lanes x float4: 8 edges per step,
// unrolled x2 -> 16 outstanding 128B gathers. Fused linear head.
__global__ void k_agg2_head(const float* __restrict__ hs2, const int* __restrict__ csr,
                            const int* __restrict__ offsets, const int* __restrict__ count,
                            const float* __restrict__ dinv, const float* __restrict__ b2,
                            const float* __restrict__ Wfc, const float* __restrict__ bfc,
                            float* __restrict__ out, int n) {
    int wid = threadIdx.x >> 6;
    int lane = threadIdx.x & 63;
    int node = blockIdx.x * 4 + wid;
    if (node >= n) return;
    int g  = lane >> 3;                 // edge group 0..7
    int f4 = lane & 7;                  // float4 index within 32-float row
    int s = offsets[node];
    int c = count[node];

    float4 a0 = make_float4(0.f, 0.f, 0.f, 0.f);
    float4 a1 = make_float4(0.f, 0.f, 0.f, 0.f);
    if (g == 0) a0 = ((const float4*)(hs2 + (size_t)node * 32))[f4];  // self loop

    for (int j = 0; j < c; j += 16) {
        int e0 = j + g;
        int e1 = j + 8 + g;
        int i0 = s + min(e0, c - 1);
        int i1 = s + min(e1, c - 1);
        int s0 = csr[i0];
        int s1 = csr[i1];
        float m0 = (e0 < c) ? 1.f : 0.f;
        float m1 = (e1 < c) ? 1.f : 0.f;
        float4 v0 = ((const float4*)(hs2 + (size_t)s0 * 32))[f4];
        float4 v1 = ((const float4*)(hs2 + (size_t)s1 * 32))[f4];
        a0.x = fmaf(m0, v0.x, a0.x); a0.y = fmaf(m0, v0.y, a0.y);
        a0.z = fmaf(m0, v0.z, a0.z); a0.w = fmaf(m0, v0.w, a0.w);
        a1.x = fmaf(m1, v1.x, a1.x); a1.y = fmaf(m1, v1.y, a1.y);
        a1.z = fmaf(m1, v1.z, a1.z); a1.w = fmaf(m1, v1.w, a1.w);
    }
    a0.x += a1.x; a0.y += a1.y; a0.z += a1.z; a0.w += a1.w;
    // fold 8 edge groups: xor 8, 16, 32
    #pragma unroll
    for (int m = 8; m <= 32; m <<= 1) {
        a0.x += __shfl_xor(a0.x, m); a0.y += __shfl_xor(a0.y, m);
        a0.z += __shfl_xor(a0.z, m); a0.w += __shfl_xor(a0.w, m);
    }

    float dv = dinv[node];
    float4 b = ((const float4*)b2)[f4];
    float4 w = ((const float4*)Wfc)[f4];
    float hx = fmaxf(fmaf(dv, a0.x, b.x), 0.f);
    float hy = fmaxf(fmaf(dv, a0.y, b.y), 0.f);
    float hz = fmaxf(fmaf(dv, a0.z, b.z), 0.f);
    float hw = fmaxf(fmaf(dv, a0.w, b.w), 0.f);
    float p = hx * w.x + hy * w.y + hz * w.z + hw * w.w;
    p += __shfl_xor(p, 1);
    p += __shfl_xor(p, 2);
    p += __shfl_xor(p, 4);
    if (lane == 0) out[node] = p + bfc[0];
}

extern "C" void kernel_launch(void* const* d_in, const int* in_sizes, int n_in,
                              void* d_out, int out_size, void* d_ws, size_t ws_size,
                              hipStream_t stream) {
    const float* x   = (const float*)d_in[0];
    const void*  ei  = d_in[1];
    const float* W1  = (const float*)d_in[2];
    const float* b1  = (const float*)d_in[3];
    const float* W2  = (const float*)d_in[4];
    const float* b2  = (const float*)d_in[5];
    const float* Wfc = (const float*)d_in[6];
    const float* bfc = (const float*)d_in[7];
    float* out = (float*)d_out;

    const int n = in_sizes[0] / 128;                 // 100000
    const int E = in_sizes[1] / 2;                   // 1600000

    size_t off = 0;
    auto alloc = [&](size_t bytes) -> void* {
        void* p = (char*)d_ws + off;
        off += (bytes + 255) & ~(size_t)255;
        return p;
    };
    int*   count   = (int*)  alloc((size_t)n * 4);
    int*   offsets = (int*)  alloc((size_t)n * 4);
    int*   cursor  = (int*)  alloc((size_t)n * 4);
    int*   totals  = (int*)  alloc(512 * 4);
    float* dinv    = (float*)alloc((size_t)n * 4);
    int*   src32   = (int*)  alloc((size_t)E * 4);
    int*   dst32   = (int*)  alloc((size_t)E * 4);
    int*   csr     = (int*)  alloc((size_t)E * 4);
    float* hs1     = (float*)alloc((size_t)n * 64 * 4);
    float* h1post  = (float*)alloc((size_t)n * 64 * 4);
    float* hs2     = (float*)alloc((size_t)n * 32 * 4);
    int*   flag    = (int*)  alloc(4);
    (void)ws_size;

    const int NB = (n + THREADS - 1) / THREADS;      // 391
    const int EB = (E + THREADS - 1) / THREADS;
    const int AG = (n + 3) / 4;

    k_detect_dtype<<<1, 1, 0, stream>>>((const unsigned int*)ei, flag);
    k_zero_int<<<NB, THREADS, 0, stream>>>(count, n);
    k_count_edges<<<EB, THREADS, 0, stream>>>(ei, flag, count, src32, dst32, E);
    k_scanA<<<NB, THREADS, 0, stream>>>(count, offsets, totals, dinv, n);
    k_scanB<<<1, 512, 0, stream>>>(totals, NB);
    k_scanC<<<NB, THREADS, 0, stream>>>(offsets, totals, cursor, n);
    k_fill_csr<<<EB, THREADS, 0, stream>>>(src32, dst32, cursor, csr, E);
    k_gemm1<<<NB, THREADS, 0, stream>>>(x, W1, dinv, hs1, n);
    k_agg1<<<AG, THREADS, 0, stream>>>(hs1, csr, offsets, count, dinv, b1, h1post, n);
    k_gemm2<<<NB, THREADS, 0, stream>>>(h1post, W2, dinv, hs2, n);
    k_agg2_head<<<AG, THREADS, 0, stream>>>(hs2, csr, offsets, count, dinv, b2, Wfc, bfc, out, n);
}

// Round 3
// 214.855 us; speedup vs baseline: 2.3597x; 1.6857x over previous
//
#include <hip/hip_runtime.h>
#include <hip/hip_bf16.h>
#include <stdint.h>

// GCN 2-layer + linear head, fp32.
// CSR build = two-level bucket counting sort (no scattered global atomics):
//  0. detect edge_index dtype (int64 vs int32)
//  1. zero coarse bucket counts (B = ceil(n/128) buckets)
//  2. k_bucket_hist: per-block LDS hist of dst>>7 -> global bucket_count
//  3. k_bucket_scan: exclusive scan of bucket_count -> bucket_base/cursor (1 block)
//  4. k_bucket_scatter: per-block LDS hist + one reserve atomic per (block,bucket),
//     write packed (src | dstlocal<<25) into bucket regions (contiguous runs)
//  5. k_fine_sort: one block per bucket; LDS hist/scan/rank over 128 local nodes;
//     coalesced csr writes; emits offsets/count/dinv
//  6. gemm1: hs1 = (x @ W1) * dinv[row]            [N,64]
//  7. agg1 : h1post = relu(dinv*(self+gather)+b1)  [N,64]  (wave/node, 8-edge ILP)
//  8. gemm2: hs2 = (h1post @ W2) * dinv[row]       [N,32]
//  9. agg2 : out = relu(dinv*(self+gather)+b2) . Wfc + bfc  (wave/node, 16-edge ILP)

#define THREADS 256
#define NBUCK_MAX 1024
#define SORT_BLOCKS 200
#define CAP 4096

__global__ void k_detect_dtype(const unsigned int* ei_words, int* flag) {
    int is64 = 1;
    for (int i = 1; i < 64; i += 2) {
        if (ei_words[i] != 0u) { is64 = 0; break; }
    }
    *flag = is64;
}

__global__ void k_zero_int(int* p, int n) {
    int i = blockIdx.x * blockDim.x + threadIdx.x;
    if (i < n) p[i] = 0;
}

__global__ void k_bucket_hist(const void* ei, const int* flag, int* bucket_count, int E, int B) {
    __shared__ int h[NBUCK_MAX];
    int t = threadIdx.x;
    for (int i = t; i < B; i += THREADS) h[i] = 0;
    __syncthreads();
    int chunk = (E + gridDim.x - 1) / gridDim.x;
    int lo = blockIdx.x * chunk;
    int hi = min(lo + chunk, E);
    bool is64 = (*flag != 0);
    const long long* p64 = (const long long*)ei;
    const int* p32 = (const int*)ei;
    for (int e = lo + t; e < hi; e += THREADS) {
        int d = is64 ? (int)p64[(size_t)E + e] : p32[E + e];
        atomicAdd(&h[d >> 7], 1);
    }
    __syncthreads();
    for (int i = t; i < B; i += THREADS) {
        int c = h[i];
        if (c) atomicAdd(&bucket_count[i], c);
    }
}

// One block of 1024 threads: exclusive scan of bucket_count[B] (B <= 1024).
__global__ void k_bucket_scan(const int* bucket_count, int* bucket_base, int* bucket_cursor, int B) {
    __shared__ int s[1024];
    int t = threadIdx.x;
    int c = (t < B) ? bucket_count[t] : 0;
    s[t] = c;
    __syncthreads();
    for (int off = 1; off < 1024; off <<= 1) {
        int v = (t >= off) ? s[t - off] : 0;
        __syncthreads();
        s[t] += v;
        __syncthreads();
    }
    if (t < B) {
        int b = s[t] - c;
        bucket_base[t] = b;
        bucket_cursor[t] = b;
    }
}

__global__ void k_bucket_scatter(const void* ei, const int* flag, int* bucket_cursor,
                                 unsigned int* packed, int E, int B) {
    __shared__ int h[NBUCK_MAX];
    __shared__ int base[NBUCK_MAX];
    int t = threadIdx.x;
    for (int i = t; i < B; i += THREADS) h[i] = 0;
    __syncthreads();
    int chunk = (E + gridDim.x - 1) / gridDim.x;
    int lo = blockIdx.x * chunk;
    int hi = min(lo + chunk, E);
    bool is64 = (*flag != 0);
    const long long* p64 = (const long long*)ei;
    const int* p32 = (const int*)ei;
    for (int e = lo + t; e < hi; e += THREADS) {
        int d = is64 ? (int)p64[(size_t)E + e] : p32[E + e];
        atomicAdd(&h[d >> 7], 1);
    }
    __syncthreads();
    for (int i = t; i < B; i += THREADS) {
        int c = h[i];
        base[i] = c ? atomicAdd(&bucket_cursor[i], c) : 0;
    }
    __syncthreads();
    for (int i = t; i < B; i += THREADS) h[i] = 0;   // reuse as within-block cursor
    __syncthreads();
    for (int e = lo + t; e < hi; e += THREADS) {
        int srcv, d;
        if (is64) { srcv = (int)p64[e]; d = (int)p64[(size_t)E + e]; }
        else      { srcv = p32[e];      d = p32[E + e]; }
        int b = d >> 7;
        int pos = base[b] + atomicAdd(&h[b], 1);
        packed[pos] = (unsigned int)srcv | ((unsigned int)(d & 127) << 25);
    }
}

// One block per bucket. LDS hist/scan/rank over the bucket's <=128 nodes,
// staged coalesced csr write; emits offsets/count/dinv.
__global__ void k_fine_sort(const unsigned int* __restrict__ packed,
                            const int* __restrict__ bucket_base,
                            const int* __restrict__ bucket_count_arr,
                            int* __restrict__ csr, int* __restrict__ offsets,
                            int* __restrict__ countp, float* __restrict__ dinv,
                            int n, int B) {
    __shared__ unsigned int words[CAP];
    __shared__ int srcstage[CAP];
    __shared__ int cnt[128];
    __shared__ int scanv[128];
    __shared__ int cursor[128];
    int b = blockIdx.x;
    int t = threadIdx.x;
    int base = bucket_base[b];
    int size = bucket_count_arr[b];
    if (t < 128) cnt[t] = 0;
    __syncthreads();
    for (int i0 = 0; i0 < size; i0 += THREADS) {
        int i = i0 + t;
        if (i < size) {
            unsigned int w = packed[base + i];
            if (i < CAP) words[i] = w;
            atomicAdd(&cnt[(w >> 25) & 127], 1);
        }
    }
    __syncthreads();
    if (t < 128) scanv[t] = cnt[t];
    __syncthreads();
    for (int off = 1; off < 128; off <<= 1) {
        int v = 0;
        if (t < 128 && t >= off) v = scanv[t - off];
        __syncthreads();
        if (t < 128) scanv[t] += v;
        __syncthreads();
    }
    if (t < 128) {
        int ex = scanv[t] - cnt[t];
        scanv[t] = ex;
        cursor[t] = ex;
        int node = (b << 7) + t;
        if (node < n) {
            offsets[node] = base + ex;
            countp[node] = cnt[t];
            dinv[node] = rsqrtf((float)(cnt[t] + 1));
        }
    }
    __syncthreads();
    if (size <= CAP) {
        for (int i0 = 0; i0 < size; i0 += THREADS) {
            int i = i0 + t;
            if (i < size) {
                unsigned int w = words[i];
                int d = (w >> 25) & 127;
                int rank = atomicAdd(&cursor[d], 1);
                srcstage[rank] = (int)(w & 0x1FFFFFFu);
            }
        }
        __syncthreads();
        for (int i0 = 0; i0 < size; i0 += THREADS) {
            int i = i0 + t;
            if (i < size) csr[base + i] = srcstage[i];
        }
    } else {
        for (int i0 = 0; i0 < size; i0 += THREADS) {   // rare fallback: direct scatter
            int i = i0 + t;
            if (i < size) {
                unsigned int w = packed[base + i];
                int d = (w >> 25) & 127;
                int rank = atomicAdd(&cursor[d], 1);
                csr[base + rank] = (int)(w & 0x1FFFFFFu);
            }
        }
    }
}

// hs1[r][j] = dinv[r] * sum_k x[r][k] * W1[k][j]   (x: [n,128], W1: [128,64])
__global__ void __launch_bounds__(THREADS, 2) k_gemm1(const float* __restrict__ x,
                                                      const float* __restrict__ W1,
                                                      const float* __restrict__ dinv,
                                                      float* __restrict__ hs1, int n) {
    __shared__ float Ws[128 * 64];
    int t = threadIdx.x;
    #pragma unroll
    for (int i = 0; i < 8; ++i) {
        int idx = t + i * THREADS;
        ((float4*)Ws)[idx] = ((const float4*)W1)[idx];
    }
    __syncthreads();

    int r = blockIdx.x * THREADS + t;
    if (r >= n) return;

    float4 acc[16];
    #pragma unroll
    for (int j = 0; j < 16; ++j) acc[j] = make_float4(0.f, 0.f, 0.f, 0.f);

    const float* xrow = x + (size_t)r * 128;
    for (int kk = 0; kk < 128; kk += 32) {
        float4 xv[8];
        #pragma unroll
        for (int q = 0; q < 8; ++q) xv[q] = ((const float4*)(xrow + kk))[q];
        #pragma unroll
        for (int c = 0; c < 32; ++c) {
            const float4 v = xv[c >> 2];
            const int m = c & 3;
            const float xc = (m == 0) ? v.x : (m == 1) ? v.y : (m == 2) ? v.z : v.w;
            const float4* wrow = (const float4*)(Ws + (kk + c) * 64);
            #pragma unroll
            for (int j = 0; j < 16; ++j) {
                float4 w = wrow[j];
                acc[j].x = fmaf(xc, w.x, acc[j].x);
                acc[j].y = fmaf(xc, w.y, acc[j].y);
                acc[j].z = fmaf(xc, w.z, acc[j].z);
                acc[j].w = fmaf(xc, w.w, acc[j].w);
            }
        }
    }
    float dv = dinv[r];
    float4* orow = (float4*)(hs1 + (size_t)r * 64);
    #pragma unroll
    for (int j = 0; j < 16; ++j) {
        float4 a = acc[j];
        orow[j] = make_float4(a.x * dv, a.y * dv, a.z * dv, a.w * dv);
    }
}

// One wave per node. 4 edge-groups x 16 lanes x float4, unrolled x2.
__global__ void k_agg1(const float* __restrict__ hs1, const int* __restrict__ csr,
                       const int* __restrict__ offsets, const int* __restrict__ count,
                       const float* __restrict__ dinv, const float* __restrict__ b1,
                       float* __restrict__ h1post, int n) {
    int wid = threadIdx.x >> 6;
    int lane = threadIdx.x & 63;
    int node = blockIdx.x * 4 + wid;
    if (node >= n) return;
    int g  = lane >> 4;
    int f4 = lane & 15;
    int s = offsets[node];
    int c = count[node];

    float4 a0 = make_float4(0.f, 0.f, 0.f, 0.f);
    float4 a1 = make_float4(0.f, 0.f, 0.f, 0.f);
    if (g == 0) a0 = ((const float4*)(hs1 + (size_t)node * 64))[f4];

    for (int j = 0; j < c; j += 8) {
        int e0 = j + g;
        int e1 = j + 4 + g;
        int i0 = s + min(e0, c - 1);
        int i1 = s + min(e1, c - 1);
        int s0 = csr[i0];
        int s1 = csr[i1];
        float m0 = (e0 < c) ? 1.f : 0.f;
        float m1 = (e1 < c) ? 1.f : 0.f;
        float4 v0 = ((const float4*)(hs1 + (size_t)s0 * 64))[f4];
        float4 v1 = ((const float4*)(hs1 + (size_t)s1 * 64))[f4];
        a0.x = fmaf(m0, v0.x, a0.x); a0.y = fmaf(m0, v0.y, a0.y);
        a0.z = fmaf(m0, v0.z, a0.z); a0.w = fmaf(m0, v0.w, a0.w);
        a1.x = fmaf(m1, v1.x, a1.x); a1.y = fmaf(m1, v1.y, a1.y);
        a1.z = fmaf(m1, v1.z, a1.z); a1.w = fmaf(m1, v1.w, a1.w);
    }
    a0.x += a1.x; a0.y += a1.y; a0.z += a1.z; a0.w += a1.w;
    a0.x += __shfl_xor(a0.x, 16); a0.y += __shfl_xor(a0.y, 16);
    a0.z += __shfl_xor(a0.z, 16); a0.w += __shfl_xor(a0.w, 16);
    a0.x += __shfl_xor(a0.x, 32); a0.y += __shfl_xor(a0.y, 32);
    a0.z += __shfl_xor(a0.z, 32); a0.w += __shfl_xor(a0.w, 32);

    if (g == 0) {
        float dv = dinv[node];
        float4 b = ((const float4*)b1)[f4];
        float4 o;
        o.x = fmaxf(fmaf(dv, a0.x, b.x), 0.f);
        o.y = fmaxf(fmaf(dv, a0.y, b.y), 0.f);
        o.z = fmaxf(fmaf(dv, a0.z, b.z), 0.f);
        o.w = fmaxf(fmaf(dv, a0.w, b.w), 0.f);
        ((float4*)(h1post + (size_t)node * 64))[f4] = o;
    }
}

// hs2[r][j] = dinv[r] * sum_k h1post[r][k] * W2[k][j]   (W2: [64,32])
__global__ void __launch_bounds__(THREADS, 2) k_gemm2(const float* __restrict__ h1,
                                                      const float* __restrict__ W2,
                                                      const float* __restrict__ dinv,
                                                      float* __restrict__ hs2, int n) {
    __shared__ float Ws[64 * 32];
    int t = threadIdx.x;
    #pragma unroll
    for (int i = 0; i < 2; ++i) {
        int idx = t + i * THREADS;
        ((float4*)Ws)[idx] = ((const float4*)W2)[idx];
    }
    __syncthreads();

    int r = blockIdx.x * THREADS + t;
    if (r >= n) return;

    float4 acc[8];
    #pragma unroll
    for (int j = 0; j < 8; ++j) acc[j] = make_float4(0.f, 0.f, 0.f, 0.f);

    const float* xrow = h1 + (size_t)r * 64;
    for (int kk = 0; kk < 64; kk += 32) {
        float4 xv[8];
        #pragma unroll
        for (int q = 0; q < 8; ++q) xv[q] = ((const float4*)(xrow + kk))[q];
        #pragma unroll
        for (int c = 0; c < 32; ++c) {
            const float4 v = xv[c >> 2];
            const int m = c & 3;
            const float xc = (m == 0) ? v.x : (m == 1) ? v.y : (m == 2) ? v.z : v.w;
            const float4* wrow = (const float4*)(Ws + (kk + c) * 32);
            #pragma unroll
            for (int j = 0; j < 8; ++j) {
                float4 w = wrow[j];
                acc[j].x = fmaf(xc, w.x, acc[j].x);
                acc[j].y = fmaf(xc, w.y, acc[j].y);
                acc[j].z = fmaf(xc, w.z, acc[j].z);
                acc[j].w = fmaf(xc, w.w, acc[j].w);
            }
        }
    }
    float dv = dinv[r];
    float4* orow = (float4*)(hs2 + (size_t)r * 32);
    #pragma unroll
    for (int j = 0; j < 8; ++j) {
        float4 a = acc[j];
        orow[j] = make_float4(a.x * dv, a.y * dv, a.z * dv, a.w * dv);
    }
}

// One wave per node. 8 edge-groups x 8 lanes x float4, unrolled x2. Fused head.
__global__ void k_agg2_head(const float* __restrict__ hs2, const int* __restrict__ csr,
                            const int* __restrict__ offsets, const int* __restrict__ count,
                            const float* __restrict__ dinv, const float* __restrict__ b2,
                            const float* __restrict__ Wfc, const float* __restrict__ bfc,
                            float* __restrict__ out, int n) {
    int wid = threadIdx.x >> 6;
    int lane = threadIdx.x & 63;
    int node = blockIdx.x * 4 + wid;
    if (node >= n) return;
    int g  = lane >> 3;
    int f4 = lane & 7;
    int s = offsets[node];
    int c = count[node];

    float4 a0 = make_float4(0.f, 0.f, 0.f, 0.f);
    float4 a1 = make_float4(0.f, 0.f, 0.f, 0.f);
    if (g == 0) a0 = ((const float4*)(hs2 + (size_t)node * 32))[f4];

    for (int j = 0; j < c; j += 16) {
        int e0 = j + g;
        int e1 = j + 8 + g;
        int i0 = s + min(e0, c - 1);
        int i1 = s + min(e1, c - 1);
        int s0 = csr[i0];
        int s1 = csr[i1];
        float m0 = (e0 < c) ? 1.f : 0.f;
        float m1 = (e1 < c) ? 1.f : 0.f;
        float4 v0 = ((const float4*)(hs2 + (size_t)s0 * 32))[f4];
        float4 v1 = ((const float4*)(hs2 + (size_t)s1 * 32))[f4];
        a0.x = fmaf(m0, v0.x, a0.x); a0.y = fmaf(m0, v0.y, a0.y);
        a0.z = fmaf(m0, v0.z, a0.z); a0.w = fmaf(m0, v0.w, a0.w);
        a1.x = fmaf(m1, v1.x, a1.x); a1.y = fmaf(m1, v1.y, a1.y);
        a1.z = fmaf(m1, v1.z, a1.z); a1.w = fmaf(m1, v1.w, a1.w);
    }
    a0.x += a1.x; a0.y += a1.y; a0.z += a1.z; a0.w += a1.w;
    #pragma unroll
    for (int m = 8; m <= 32; m <<= 1) {
        a0.x += __shfl_xor(a0.x, m); a0.y += __shfl_xor(a0.y, m);
        a0.z += __shfl_xor(a0.z, m); a0.w += __shfl_xor(a0.w, m);
    }

    float dv = dinv[node];
    float4 b = ((const float4*)b2)[f4];
    float4 w = ((const float4*)Wfc)[f4];
    float hx = fmaxf(fmaf(dv, a0.x, b.x), 0.f);
    float hy = fmaxf(fmaf(dv, a0.y, b.y), 0.f);
    float hz = fmaxf(fmaf(dv, a0.z, b.z), 0.f);
    float hw = fmaxf(fmaf(dv, a0.w, b.w), 0.f);
    float p = hx * w.x + hy * w.y + hz * w.z + hw * w.w;
    p += __shfl_xor(p, 1);
    p += __shfl_xor(p, 2);
    p += __shfl_xor(p, 4);
    if (lane == 0) out[node] = p + bfc[0];
}

extern "C" void kernel_launch(void* const* d_in, const int* in_sizes, int n_in,
                              void* d_out, int out_size, void* d_ws, size_t ws_size,
                              hipStream_t stream) {
    const float* x   = (const float*)d_in[0];
    const void*  ei  = d_in[1];
    const float* W1  = (const float*)d_in[2];
    const float* b1  = (const float*)d_in[3];
    const float* W2  = (const float*)d_in[4];
    const float* b2  = (const float*)d_in[5];
    const float* Wfc = (const float*)d_in[6];
    const float* bfc = (const float*)d_in[7];
    float* out = (float*)d_out;

    const int n = in_sizes[0] / 128;                 // 100000
    const int E = in_sizes[1] / 2;                   // 1600000
    const int B = (n + 127) >> 7;                    // 782 buckets (<=1024)

    size_t off = 0;
    auto alloc = [&](size_t bytes) -> void* {
        void* p = (char*)d_ws + off;
        off += (bytes + 255) & ~(size_t)255;
        return p;
    };
    int*   bucket_count  = (int*)alloc((size_t)NBUCK_MAX * 4);
    int*   bucket_base   = (int*)alloc((size_t)NBUCK_MAX * 4);
    int*   bucket_cursor = (int*)alloc((size_t)NBUCK_MAX * 4);
    unsigned int* packed = (unsigned int*)alloc((size_t)E * 4);
    int*   csr     = (int*)  alloc((size_t)E * 4);
    int*   offsets = (int*)  alloc((size_t)n * 4);
    int*   count   = (int*)  alloc((size_t)n * 4);
    float* dinv    = (float*)alloc((size_t)n * 4);
    float* hs1     = (float*)alloc((size_t)n * 64 * 4);
    float* h1post  = (float*)alloc((size_t)n * 64 * 4);
    float* hs2     = (float*)alloc((size_t)n * 32 * 4);
    int*   flag    = (int*)  alloc(4);
    (void)ws_size;

    const int NB = (n + THREADS - 1) / THREADS;
    const int AG = (n + 3) / 4;

    k_detect_dtype<<<1, 1, 0, stream>>>((const unsigned int*)ei, flag);
    k_zero_int<<<(B + THREADS - 1) / THREADS, THREADS, 0, stream>>>(bucket_count, B);
    k_bucket_hist<<<SORT_BLOCKS, THREADS, 0, stream>>>(ei, flag, bucket_count, E, B);
    k_bucket_scan<<<1, 1024, 0, stream>>>(bucket_count, bucket_base, bucket_cursor, B);
    k_bucket_scatter<<<SORT_BLOCKS, THREADS, 0, stream>>>(ei, flag, bucket_cursor, packed, E, B);
    k_fine_sort<<<B, THREADS, 0, stream>>>(packed, bucket_base, bucket_count,
                                           csr, offsets, count, dinv, n, B);
    k_gemm1<<<NB, THREADS, 0, stream>>>(x, W1, dinv, hs1, n);
    k_agg1<<<AG, THREADS, 0, stream>>>(hs1, csr, offsets, count, dinv, b1, h1post, n);
    k_gemm2<<<NB, THREADS, 0, stream>>>(h1post, W2, dinv, hs2, n);
    k_agg2_head<<<AG, THREADS, 0, stream>>>(hs2, csr, offsets, count, dinv, b2, Wfc, bfc, out, n);
}